// Round 3
// baseline (1652.798 us; speedup 1.0000x reference)
//
#include <hip/hip_runtime.h>
#include <cstddef>
#include <cstdint>

typedef float f2 __attribute__((ext_vector_type(2)));

__device__ __forceinline__ float fast_exp2(float x) {
  return __builtin_amdgcn_exp2f(x);
}
__device__ __forceinline__ float fast_log2(float x) {
  return __builtin_amdgcn_logf(x);
}

namespace {
constexpr int Bc = 256, Tc = 1024, Kc = 128;
constexpr float L2E = 1.4426950408889634f;
constexpr float LN2 = 0.6931471805599453f;
}

// One block = one batch row = ONE wave (64 lanes). Lane l owns output tags
// j0=2l, j1=2l+1. Full-K matvec per lane: E columns held in registers
// (EA/EB, 128 f2 = 256 regs across the unified VGPR/AGPR file), packed over
// adjacent i so v_pk_fma_f32 needs no splat:
//   acc += {p[i],p[i+1]} * {E[i][j],E[i+1][j]}.
// p (exp-domain alpha, 128 floats) lives in LDS; single-wave lockstep +
// in-order DS pipe make write->read ordering safe with NO barrier.
// Rescale: scale_t = 2^-exponent(p2[0]) with p2[0] taken from the loop-top
// broadcast read (off the critical path); Mi accumulates the exact shift.
__global__ __launch_bounds__(64, 1) void crf_forward_kernel(
    const float* __restrict__ hs,      // [B,T,K]
    const float* __restrict__ trans,   // [K,K]
    const float* __restrict__ start_t, // [K]
    const float* __restrict__ end_t,   // [K]
    float* __restrict__ out)           // [B]
{
  __shared__ __align__(16) float p2[Kc];

  const int lane = (int)threadIdx.x;
  const int b = (int)blockIdx.x;
  const float* __restrict__ emis = hs + (size_t)b * Tc * Kc;
  const f2* __restrict__ emis2 = reinterpret_cast<const f2*>(emis);
  const f2* __restrict__ trans2 = reinterpret_cast<const f2*>(trans);

  // EA[m] = {E[2m][j0], E[2m+1][j0]}, EB[m] = {E[2m][j1], E[2m+1][j1]},
  // E = 2^(trans * log2e).  trans2[i*64+lane] = {trans[i][j0], trans[i][j1]}.
  f2 EA[64], EB[64];
#pragma unroll
  for (int m = 0; m < 64; ++m) {
    f2 t0 = trans2[(2 * m) * 64 + lane];
    f2 t1 = trans2[(2 * m + 1) * 64 + lane];
    EA[m] = (f2){fast_exp2(t0.x * L2E), fast_exp2(t1.x * L2E)};
    EB[m] = (f2){fast_exp2(t0.y * L2E), fast_exp2(t1.y * L2E)};
  }

  // Emission prefetch ring, slot (t-1)&3; preload t = 1..4.
  f2 er[4];
#pragma unroll
  for (int d = 0; d < 4; ++d) er[d] = emis2[(size_t)(1 + d) * 64 + lane];

  float Mf, pA, pB;
  int Mi = 0;
  {
    float a00 = (start_t[0] + emis[0]) * L2E;   // identical on all lanes
    f2 s2 = reinterpret_cast<const f2*>(start_t)[lane];
    f2 e0 = emis2[lane];
    pA = fast_exp2(fmaf(s2.x + e0.x, L2E, -a00));
    pB = fast_exp2(fmaf(s2.y + e0.y, L2E, -a00));
    Mf = a00;
    reinterpret_cast<f2*>(p2)[lane] = (f2){pA, pB};
  }
  asm volatile("" ::: "memory");   // p2 write stays before the first reads

  auto step = [&](int t, int u) {
    const float4* pv = reinterpret_cast<const float4*>(p2);
    f2 a0 = (f2){0.f, 0.f}, a1 = (f2){0.f, 0.f};
    f2 b0 = (f2){0.f, 0.f}, b1 = (f2){0.f, 0.f};
    uint32_t p00 = 0;
#pragma unroll
    for (int k = 0; k < 32; ++k) {
      float4 q = pv[k];                 // wave-uniform -> LDS broadcast
      if (k == 0) p00 = __float_as_uint(q.x);
      f2 plo = (f2){q.x, q.y};
      f2 phi = (f2){q.z, q.w};
      a0 += plo * EA[2 * k];            // v_pk_fma_f32, no splats
      a1 += phi * EA[2 * k + 1];
      b0 += plo * EB[2 * k];
      b1 += phi * EB[2 * k + 1];
    }
    // Scale from current p2[0] exponent (known since k=0 -> off critical path).
    uint32_t E0 = (p00 >> 23) & 0xffu;
    Mi += (int)E0 - 127;
    float scale = __uint_as_float((254u - E0) << 23);   // 2^(127-E0)
    f2 e = er[u];
    float eeA = fast_exp2(e.x * L2E);
    float eeB = fast_exp2(e.y * L2E);
    int tn = t + 4;
    if (tn > Tc - 1) tn = Tc - 1;
    er[u] = emis2[(size_t)tn * 64 + lane];              // refill ring slot
    pA = ((a0.x + a0.y) + (a1.x + a1.y)) * scale * eeA;
    pB = ((b0.x + b0.y) + (b1.x + b1.y)) * scale * eeB;
    asm volatile("" ::: "memory");      // reads above stay before this write
    reinterpret_cast<f2*>(p2)[lane] = (f2){pA, pB};
    asm volatile("" ::: "memory");      // write stays before next step's reads
  };

  for (int tb = 1; tb + 3 < Tc; tb += 4) {
    step(tb, 0); step(tb + 1, 1); step(tb + 2, 2); step(tb + 3, 3);
  }
  step(Tc - 3, 0); step(Tc - 2, 1); step(Tc - 1, 2);

  // logZ = ln2 * (Mf + Mi + log2(sum_j p[j] * 2^(end2[j])))
  f2 en = reinterpret_cast<const f2*>(end_t)[lane];
  float v = pA * fast_exp2(en.x * L2E) + pB * fast_exp2(en.y * L2E);
#pragma unroll
  for (int off = 32; off; off >>= 1) v += __shfl_down(v, off);
  if (lane == 0) out[b] = (Mf + (float)Mi + fast_log2(v)) * LN2;
}

extern "C" void kernel_launch(void* const* d_in, const int* in_sizes, int n_in,
                              void* d_out, int out_size, void* d_ws, size_t ws_size,
                              hipStream_t stream) {
  const float* hs    = (const float*)d_in[0];
  const float* trans = (const float*)d_in[1];
  const float* st    = (const float*)d_in[2];
  const float* en    = (const float*)d_in[3];
  crf_forward_kernel<<<dim3(Bc), dim3(64), 0, stream>>>(hs, trans, st, en, (float*)d_out);
}

// Round 4
// 567.369 us; speedup vs baseline: 2.9131x; 2.9131x over previous
//
#include <hip/hip_runtime.h>
#include <cstddef>
#include <cstdint>

typedef float f2 __attribute__((ext_vector_type(2)));
typedef float f32x4 __attribute__((ext_vector_type(4)));
typedef short bf16x8 __attribute__((ext_vector_type(8)));   // 8 bf16 = 4 VGPRs

__device__ __forceinline__ float fast_exp2(float x) { return __builtin_amdgcn_exp2f(x); }
__device__ __forceinline__ float fast_log2(float x) { return __builtin_amdgcn_logf(x); }

// bf16 round-to-nearest-even from f32.
__device__ __forceinline__ short bf16rne(float x) {
  uint32_t u = __float_as_uint(x);
  u += 0x7fffu + ((u >> 16) & 1u);
  return (short)(u >> 16);
}

namespace {
constexpr int Bc = 256, Tc = 1024, Kc = 128;
constexpr float L2E = 1.4426950408889634f;
constexpr float LN2 = 0.6931471805599453f;
}

// One block = one batch row = ONE wave. The K=128 all-to-all (every output
// tag needs every p_i) runs on the MFMA operand-broadcast network instead of
// LDS broadcast reads (R2's 768 cyc/step cost):
//   s = E^T (A operand, 8 M-tiles x 4 K-tiles, bf16, register-resident)
//       x p (B operand, col 0 only; cols 1-15 zero).
// C col 0 -> s_j on lanes {0,16,32,48} (j = 16n + 4(lane>>4) + reg).
// Epilogue is j-distributed: bounce s through LDS (tiny, conflict-free),
// each lane applies exact pow2 rescale + exp2(emission) to j=2l,2l+1, packs
// bf16, publishes; lanes {0,16,32,48} gather next B-frags. Single-wave
// in-order DS pipe => no barriers anywhere.
__global__ __launch_bounds__(64, 1) void crf_forward_kernel(
    const float* __restrict__ hs,      // [B,T,K]
    const float* __restrict__ trans,   // [K,K]
    const float* __restrict__ start_t, // [K]
    const float* __restrict__ end_t,   // [K]
    float* __restrict__ out)           // [B]
{
  __shared__ __align__(16) float sE[Kc];          // s bounce (f32)
  __shared__ __align__(16) uint32_t pb[Kc / 2];   // packed bf16 p pairs

  const int lane = (int)threadIdx.x;
  const int b = (int)blockIdx.x;
  const int m  = lane & 15;     // A row / C col
  const int kq = lane >> 4;     // k-quad
  const bool act = (m == 0);    // lanes 0,16,32,48: B col 0 / C col 0

  const float* __restrict__ emis = hs + (size_t)b * Tc * Kc;
  const f2* __restrict__ emis2 = reinterpret_cast<const f2*>(emis);

  // A-frags: A[n][t] = E^T tile (rows j=16n+m, cols k=32t+8kq+j'), bf16.
  // E = 2^(trans * log2e). MFMA reads these from AGPRs (unified file).
  bf16x8 A[8][4];
#pragma unroll
  for (int n = 0; n < 8; ++n) {
#pragma unroll
    for (int tt = 0; tt < 4; ++tt) {
      bf16x8 a;
#pragma unroll
      for (int j = 0; j < 8; ++j) {
        float tv = trans[(size_t)(32 * tt + 8 * kq + j) * Kc + 16 * n + m];
        a[j] = bf16rne(fast_exp2(tv * L2E));
      }
      A[n][tt] = a;
    }
  }

  // B-frags: p as bf16. Cols 1..15 stay zero forever (init here, reads below
  // are exec-masked to act lanes only).
  bf16x8 Bf[4];
#pragma unroll
  for (int tt = 0; tt < 4; ++tt) Bf[tt] = (bf16x8)(short)0;

  // Emission prefetch ring (coalesced f2/lane), slot (t-1)&3, preload t=1..4.
  f2 er[4];
#pragma unroll
  for (int d = 0; d < 4; ++d) er[d] = emis2[(size_t)(1 + d) * 64 + lane];

  float Mf, pA, pB;
  int Mi = 0;
  {
    f2 sv = reinterpret_cast<const f2*>(start_t)[lane];
    f2 e0 = emis2[lane];
    float a00 = (start_t[0] + emis[0]) * L2E;    // lane-uniform
    Mf = a00;
    pA = fast_exp2(fmaf(sv.x + e0.x, L2E, -a00));
    pB = fast_exp2(fmaf(sv.y + e0.y, L2E, -a00));
    uint32_t pk = (uint32_t)(uint16_t)bf16rne(pA) |
                  ((uint32_t)(uint16_t)bf16rne(pB) << 16);
    pb[lane] = pk;
    asm volatile("" ::: "memory");
    if (act) {
#pragma unroll
      for (int tt = 0; tt < 4; ++tt)
        Bf[tt] = reinterpret_cast<const bf16x8*>(pb)[4 * tt + kq];
    }
    asm volatile("" ::: "memory");
  }

  auto step = [&](int t, int u) {
    // Emission exp2 for THIS step + ring refill (independent of MFMA ->
    // compiler schedules into the MFMA window).
    f2 e = er[u];
    float eeA = fast_exp2(e.x * L2E);
    float eeB = fast_exp2(e.y * L2E);
    int tn = t + 4;
    if (tn > Tc - 1) tn = Tc - 1;
    er[u] = emis2[(size_t)tn * 64 + lane];

    // s = E^T * p : 8 C-tiles, each a 4-chain over K-tiles.
    f32x4 C[8];
#pragma unroll
    for (int n = 0; n < 8; ++n) {
      f32x4 c = {0.f, 0.f, 0.f, 0.f};
#pragma unroll
      for (int tt = 0; tt < 4; ++tt)
        c = __builtin_amdgcn_mfma_f32_16x16x32_bf16(A[n][tt], Bf[tt], c, 0, 0, 0);
      C[n] = c;
    }

    // Dump C col 0 -> sE[j] (act lanes; banks 16n+4kq distinct, no conflict).
    if (act) {
#pragma unroll
      for (int n = 0; n < 8; ++n)
        reinterpret_cast<f32x4*>(sE)[4 * n + kq] = C[n];
    }
    asm volatile("" ::: "memory");   // in-order DS pipe: RAW safe, just pin order
    f2 s2 = reinterpret_cast<const f2*>(sE)[lane];   // j = 2l, 2l+1

    // Exact pow2 rescale from exponent of s[0] (readfirstlane -> uniform).
    int su = __builtin_amdgcn_readfirstlane(__float_as_int(s2.x));
    int E0 = (su >> 23) & 0xff;
    Mi += E0 - 127;
    float scale = __int_as_float((254 - E0) << 23);  // 2^(127-E0)
    pA = s2.x * scale * eeA;
    pB = s2.y * scale * eeB;

    uint32_t pk = (uint32_t)(uint16_t)bf16rne(pA) |
                  ((uint32_t)(uint16_t)bf16rne(pB) << 16);
    asm volatile("" ::: "memory");
    pb[lane] = pk;
    asm volatile("" ::: "memory");
    if (act) {   // gather next B-frags: dwords 16t+4kq..+3 = frag dwords 0..3
#pragma unroll
      for (int tt = 0; tt < 4; ++tt)
        Bf[tt] = reinterpret_cast<const bf16x8*>(pb)[4 * tt + kq];
    }
    asm volatile("" ::: "memory");
  };

  for (int tb = 1; tb + 3 < Tc; tb += 4) {
    step(tb, 0); step(tb + 1, 1); step(tb + 2, 2); step(tb + 3, 3);
  }
  step(Tc - 3, 0); step(Tc - 2, 1); step(Tc - 1, 2);

  // logZ = ln2 * (Mf + Mi + log2(sum_j p_j * 2^(end_j*log2e)))
  f2 en2 = reinterpret_cast<const f2*>(end_t)[lane];
  float v = pA * fast_exp2(en2.x * L2E) + pB * fast_exp2(en2.y * L2E);
#pragma unroll
  for (int off = 32; off; off >>= 1) v += __shfl_down(v, off);
  if (lane == 0) out[b] = (Mf + (float)Mi + fast_log2(v)) * LN2;
}

extern "C" void kernel_launch(void* const* d_in, const int* in_sizes, int n_in,
                              void* d_out, int out_size, void* d_ws, size_t ws_size,
                              hipStream_t stream) {
  const float* hs    = (const float*)d_in[0];
  const float* trans = (const float*)d_in[1];
  const float* st    = (const float*)d_in[2];
  const float* en    = (const float*)d_in[3];
  crf_forward_kernel<<<dim3(Bc), dim3(64), 0, stream>>>(hs, trans, st, en, (float*)d_out);
}

// Round 6
// 453.662 us; speedup vs baseline: 3.6432x; 1.2506x over previous
//
#include <hip/hip_runtime.h>
#include <cstddef>
#include <cstdint>

typedef float f32x4 __attribute__((ext_vector_type(4)));
typedef short bf16x8 __attribute__((ext_vector_type(8)));

__device__ __forceinline__ float fast_exp2(float x) { return __builtin_amdgcn_exp2f(x); }
__device__ __forceinline__ float fast_log2(float x) { return __builtin_amdgcn_logf(x); }

__device__ __forceinline__ short bf16rne(float x) {
  uint32_t u = __float_as_uint(x);
  u += 0x7fffu + ((u >> 16) & 1u);
  return (short)(u >> 16);
}

// Workgroup barrier WITHOUT the vmcnt(0) drain __syncthreads carries:
// orders LDS only; global prefetch loads stay in flight (R2-verified).
__device__ __forceinline__ void bar_lds() {
  asm volatile("s_waitcnt lgkmcnt(0)\n\ts_barrier" ::: "memory");
}

namespace {
constexpr int Bc = 256, Tc = 1024, Kc = 128;
constexpr int ROWS = 16;                  // batch rows per block (B columns)
constexpr float L2E = 1.4426950408889634f;
constexpr float LN2 = 0.6931471805599453f;
constexpr int PSTR = 136;                 // pL row stride in bf16 (+8 pad: 272 B, 16-aligned)
}

// 16 blocks x 256 threads (4 waves, 1/SIMD). Block handles batch rows
// 16*blockIdx..+15 via the 16 MFMA B/C columns (col = lane&15, R4-verified).
// Wave w owns n-tiles {2w, 2w+1} (output tags j in [32w, 32w+32)):
// 8x mfma_f32_16x16x32_bf16 per step per SIMD (155 cyc pipe vs R4's 621).
// p exchange: bf16 [16 rows x 128 tags] in double-buffered LDS, ONE bar_lds
// per step. Per-row pow2 rescale uses the ONE-STEP-LAGGED exponent of
// s[b,0] (read in the previous post-barrier window) -> nothing on the
// critical path waits for a fresh reduction; bf16 range makes lag safe.
// D_t = D_{t-1} + E0_{t-1} accumulates the exact shift per row.
__global__ __launch_bounds__(256, 1) void crf_forward_kernel(
    const float* __restrict__ hs,      // [B,T,K]
    const float* __restrict__ trans,   // [K,K]
    const float* __restrict__ start_t, // [K]
    const float* __restrict__ end_t,   // [K]
    float* __restrict__ out)           // [B]
{
  __shared__ __align__(16) unsigned short pL[2][ROWS][PSTR];  // p̂ (bf16)
  __shared__ float sSc[2][ROWS];                              // s[b,0] per step
  __shared__ float vred[256];                                 // final reduce

  const int tid = (int)threadIdx.x;
  const int w = tid >> 6;        // wave 0..3
  const int lane = tid & 63;
  const int b = lane & 15;       // B/C column = batch row within block; A row
  const int kq = lane >> 4;      // k-quad / C row-quad
  const int brow = (int)blockIdx.x * ROWS + b;
  const float* __restrict__ eb = hs + (size_t)brow * Tc * Kc;

  const int jb0 = 32 * w + 4 * kq;        // j-base, n-tile 2w   (4 consecutive j)
  const int jb1 = 32 * w + 16 + 4 * kq;   // j-base, n-tile 2w+1

  // A-frags: E^T tiles, rows j = 16*(2w+np)+b, k = 32*tt+8*kq+jj (R4 pattern).
  bf16x8 A[2][4];
#pragma unroll
  for (int np = 0; np < 2; ++np)
#pragma unroll
    for (int tt = 0; tt < 4; ++tt) {
      bf16x8 a;
#pragma unroll
      for (int jj = 0; jj < 8; ++jj) {
        float tv = trans[(size_t)(32 * tt + 8 * kq + jj) * Kc + 16 * (2 * w + np) + b];
        a[jj] = bf16rne(fast_exp2(tv * L2E));
      }
      A[np][tt] = a;
    }

  // Emission prefetch ring: er[u][np] = emis[b][t][jb..jb+3], preload t=1..4.
  f32x4 er[4][2];
#pragma unroll
  for (int d = 0; d < 4; ++d) {
    er[d][0] = *(const f32x4*)&eb[(size_t)(1 + d) * Kc + jb0];
    er[d][1] = *(const f32x4*)&eb[(size_t)(1 + d) * Kc + jb1];
  }

  // p̂_0 = 2^((start+e0)*L2E) (no offset; bf16 range is ample). Write buf 0.
#pragma unroll
  for (int np = 0; np < 2; ++np) {
    const int jb = np ? jb1 : jb0;
    f32x4 sv = *(const f32x4*)&start_t[jb];
    f32x4 e0 = *(const f32x4*)&eb[jb];
    uint32_t d0 = (uint32_t)(uint16_t)bf16rne(fast_exp2((sv.x + e0.x) * L2E)) |
                  ((uint32_t)(uint16_t)bf16rne(fast_exp2((sv.y + e0.y) * L2E)) << 16);
    uint32_t d1 = (uint32_t)(uint16_t)bf16rne(fast_exp2((sv.z + e0.z) * L2E)) |
                  ((uint32_t)(uint16_t)bf16rne(fast_exp2((sv.w + e0.w) * L2E)) << 16);
    *(uint2*)&pL[0][b][jb] = make_uint2(d0, d1);
  }
  bar_lds();
  bf16x8 Bf[4];
#pragma unroll
  for (int tt = 0; tt < 4; ++tt)
    Bf[tt] = *(const bf16x8*)&pL[0][b][32 * tt + 8 * kq];

  float scale = 1.0f;   // 2^-E0_{t-1}, lag-1
  int curE0 = 0;
  int Mi = 0;           // per-row accumulated exponent D
  f32x4 pf0 = {0, 0, 0, 0}, pf1 = {0, 0, 0, 0};   // final-step p̂ (f32)

  auto step = [&](int t, int u) {
    // s = E^T * p̂ for 16 rows: 2 n-tiles x 4 k-tiles.
    f32x4 C[2];
#pragma unroll
    for (int np = 0; np < 2; ++np) {
      f32x4 c = {0.f, 0.f, 0.f, 0.f};
#pragma unroll
      for (int tt = 0; tt < 4; ++tt)
        c = __builtin_amdgcn_mfma_f32_16x16x32_bf16(A[np][tt], Bf[tt], c, 0, 0, 0);
      C[np] = c;
    }
    // scale * 2^(e*L2E) in the MFMA shadow (independent of C).
    f32x4 se0, se1;
    {
      f32x4 e = er[u][0];
      se0.x = scale * fast_exp2(e.x * L2E); se0.y = scale * fast_exp2(e.y * L2E);
      se0.z = scale * fast_exp2(e.z * L2E); se0.w = scale * fast_exp2(e.w * L2E);
      e = er[u][1];
      se1.x = scale * fast_exp2(e.x * L2E); se1.y = scale * fast_exp2(e.y * L2E);
      se1.z = scale * fast_exp2(e.z * L2E); se1.w = scale * fast_exp2(e.w * L2E);
    }
    Mi += curE0;
    // Refill ring 4 steps ahead (loads stay in flight across bar_lds).
    int tn = t + 4;
    if (tn > Tc - 1) tn = Tc - 1;
    er[u][0] = *(const f32x4*)&eb[(size_t)tn * Kc + jb0];
    er[u][1] = *(const f32x4*)&eb[(size_t)tn * Kc + jb1];

    const int buf = t & 1;
    // Epilogue: p̂ = C * (scale*ee), pack bf16, publish.
    {
      f32x4 p;
      p.x = C[0].x * se0.x; p.y = C[0].y * se0.y;
      p.z = C[0].z * se0.z; p.w = C[0].w * se0.w;
      pf0 = p;
      uint32_t d0 = (uint32_t)(uint16_t)bf16rne(p.x) | ((uint32_t)(uint16_t)bf16rne(p.y) << 16);
      uint32_t d1 = (uint32_t)(uint16_t)bf16rne(p.z) | ((uint32_t)(uint16_t)bf16rne(p.w) << 16);
      *(uint2*)&pL[buf][b][jb0] = make_uint2(d0, d1);
      p.x = C[1].x * se1.x; p.y = C[1].y * se1.y;
      p.z = C[1].z * se1.z; p.w = C[1].w * se1.w;
      pf1 = p;
      d0 = (uint32_t)(uint16_t)bf16rne(p.x) | ((uint32_t)(uint16_t)bf16rne(p.y) << 16);
      d1 = (uint32_t)(uint16_t)bf16rne(p.z) | ((uint32_t)(uint16_t)bf16rne(p.w) << 16);
      *(uint2*)&pL[buf][b][jb1] = make_uint2(d0, d1);
    }
    // s[b,0] lives in C[0] reg0 on wave 0, kq==0 lanes (col=b, row=0).
    if (w == 0 && kq == 0) sSc[buf][b] = C[0].x;
    bar_lds();
    // Post-barrier window: next B-frags + lagged scale for the NEXT step.
#pragma unroll
    for (int tt = 0; tt < 4; ++tt)
      Bf[tt] = *(const bf16x8*)&pL[buf][b][32 * tt + 8 * kq];
    float s0 = sSc[buf][b];
    uint32_t ex = (__float_as_uint(s0) >> 23) & 0xffu;
    curE0 = (int)ex - 127;
    scale = __uint_as_float((254u - ex) << 23);   // 2^(127-ex)
  };

  for (int tb = 1; tb + 3 < Tc; tb += 4) {
    step(tb, 0); step(tb + 1, 1); step(tb + 2, 2); step(tb + 3, 3);
  }
  step(Tc - 3, 0); step(Tc - 2, 1); step(Tc - 1, 2);

  // logZ_b = ln2 * (Mi_b + log2(sum_j p̂_T[b,j] * 2^(end_j*L2E)))
  float v;
  {
    f32x4 en = *(const f32x4*)&end_t[jb0];
    v = pf0.x * fast_exp2(en.x * L2E) + pf0.y * fast_exp2(en.y * L2E) +
        pf0.z * fast_exp2(en.z * L2E) + pf0.w * fast_exp2(en.w * L2E);
    en = *(const f32x4*)&end_t[jb1];
    v += pf1.x * fast_exp2(en.x * L2E) + pf1.y * fast_exp2(en.y * L2E) +
         pf1.z * fast_exp2(en.z * L2E) + pf1.w * fast_exp2(en.w * L2E);
  }
  vred[(w * 4 + kq) * 16 + b] = v;
  bar_lds();
  if (tid < 16) {   // lane b=tid of wave 0: holds Mi for row tid
    float S = 0.f;
#pragma unroll
    for (int g = 0; g < 16; ++g) S += vred[g * 16 + tid];
    out[(int)blockIdx.x * ROWS + tid] = ((float)Mi + fast_log2(S)) * LN2;
  }
}

extern "C" void kernel_launch(void* const* d_in, const int* in_sizes, int n_in,
                              void* d_out, int out_size, void* d_ws, size_t ws_size,
                              hipStream_t stream) {
  const float* hs    = (const float*)d_in[0];
  const float* trans = (const float*)d_in[1];
  const float* st    = (const float*)d_in[2];
  const float* en    = (const float*)d_in[3];
  crf_forward_kernel<<<dim3(Bc / ROWS), dim3(256), 0, stream>>>(hs, trans, st, en, (float*)d_out);
}

// Round 7
// 322.049 us; speedup vs baseline: 5.1321x; 1.4087x over previous
//
#include <hip/hip_runtime.h>
#include <cstddef>
#include <cstdint>

typedef float f2    __attribute__((ext_vector_type(2)));
typedef float f32x4 __attribute__((ext_vector_type(4)));
typedef short bf16x8 __attribute__((ext_vector_type(8)));

__device__ __forceinline__ float fast_exp2(float x) { return __builtin_amdgcn_exp2f(x); }
__device__ __forceinline__ float fast_log2(float x) { return __builtin_amdgcn_logf(x); }

__device__ __forceinline__ short bf16rne(float x) {
  uint32_t u = __float_as_uint(x);
  u += 0x7fffu + ((u >> 16) & 1u);
  return (short)(u >> 16);
}

// LDS-only barrier: no vmcnt drain, global prefetch stays in flight.
__device__ __forceinline__ void bar_lds() {
  asm volatile("s_waitcnt lgkmcnt(0)\n\ts_barrier" ::: "memory");
}

namespace {
constexpr int Bc = 256, Tc = 1024, Kc = 128;
constexpr int ROWS = 16;
constexpr int HALF = Tc / 2;              // 512
constexpr float L2E = 1.4426950408889634f;
constexpr float LN2 = 0.6931471805599453f;
constexpr int PSTR = 136;
// Workspace layout (floats): PF[256][128], PB[256][128], MIF[256], MIB[256]
constexpr int WS_PB  = Bc * Kc;           // 32768
constexpr int WS_MIF = 2 * Bc * Kc;       // 65536
constexpr int WS_MIB = WS_MIF + Bc;       // 65792
}

// Bidirectional CRF: Z_b = alpha_511^T . v_512.
//   fwd (blocks 0..15):  alpha_t = (E^T alpha_{t-1}) .* ee_t,  511 steps.
//   bwd (blocks 16..31): w_t = ee_t .* v_{t+1}; v_t = E w_t,   512 matvecs,
//                        emissions consumed descending 1023..512.
// Both use the R6-verified machinery: 16 batch rows in the 16 MFMA B/C
// columns, 4 waves x 2 n-tiles, bf16 LDS exchange (1 bar_lds/step), lag-1
// exact pow2 rescale from s[b,0]'s exponent. MFMA accumulation split 2+2
// (independent chains) to cut dependent latency. Results land in d_ws;
// crf_combine (2nd launch, stream-ordered) does the 128-length dots.
__global__ __launch_bounds__(256, 1) void crf_fwd_bwd_kernel(
    const float* __restrict__ hs,
    const float* __restrict__ trans,
    const float* __restrict__ start_t,
    const float* __restrict__ end_t,
    float* __restrict__ ws)
{
  __shared__ __align__(16) unsigned short pL[2][ROWS][PSTR];
  __shared__ float sSc[2][ROWS];

  const int tid = (int)threadIdx.x;
  const int w = tid >> 6;
  const int lane = tid & 63;
  const int b = lane & 15;
  const int kq = lane >> 4;
  const bool fwd = ((int)blockIdx.x) < 16;
  const int rb = (int)blockIdx.x & 15;
  const int brow = rb * ROWS + b;
  const float* __restrict__ eb = hs + (size_t)brow * Tc * Kc;

  const int jb0 = 32 * w + 4 * kq;
  const int jb1 = 32 * w + 16 + 4 * kq;

  // A-frags. fwd: A[m][k] = E[k][16n+m] (E^T); bwd: A[m][k] = E[16n+m][k].
  bf16x8 A[2][4];
#pragma unroll
  for (int np = 0; np < 2; ++np)
#pragma unroll
    for (int tt = 0; tt < 4; ++tt) {
      bf16x8 a;
#pragma unroll
      for (int jj = 0; jj < 8; ++jj) {
        const int kg = 32 * tt + 8 * kq + jj;
        const int rg = 16 * (2 * w + np) + b;
        float tv = fwd ? trans[(size_t)kg * Kc + rg] : trans[(size_t)rg * Kc + kg];
        a[jj] = bf16rne(fast_exp2(tv * L2E));
      }
      A[np][tt] = a;
    }

  // Emission ring. Slot d holds row (fwd ? 1+d : 1022-d).
  f32x4 er[4][2];
#pragma unroll
  for (int d = 0; d < 4; ++d) {
    const size_t rrow = fwd ? (size_t)(1 + d) : (size_t)(1022 - d);
    er[d][0] = *(const f32x4*)&eb[rrow * Kc + jb0];
    er[d][1] = *(const f32x4*)&eb[rrow * Kc + jb1];
  }

  // Init vector: fwd p0 = 2^((start+e_0)L2E); bwd w_1023 = 2^((end+e_1023)L2E).
#pragma unroll
  for (int np = 0; np < 2; ++np) {
    const int jb = np ? jb1 : jb0;
    f32x4 sv = fwd ? *(const f32x4*)&start_t[jb] : *(const f32x4*)&end_t[jb];
    f32x4 e0 = *(const f32x4*)&eb[(fwd ? (size_t)0 : (size_t)(Tc - 1)) * Kc + jb];
    uint32_t d0 = (uint32_t)(uint16_t)bf16rne(fast_exp2((sv.x + e0.x) * L2E)) |
                  ((uint32_t)(uint16_t)bf16rne(fast_exp2((sv.y + e0.y) * L2E)) << 16);
    uint32_t d1 = (uint32_t)(uint16_t)bf16rne(fast_exp2((sv.z + e0.z) * L2E)) |
                  ((uint32_t)(uint16_t)bf16rne(fast_exp2((sv.w + e0.w) * L2E)) << 16);
    *(uint2*)&pL[0][b][jb] = make_uint2(d0, d1);
  }
  bar_lds();
  bf16x8 Bf[4];
#pragma unroll
  for (int tt = 0; tt < 4; ++tt)
    Bf[tt] = *(const bf16x8*)&pL[0][b][32 * tt + 8 * kq];

  float scale = 1.0f;
  int curE0 = 0;
  int Mi = 0;
  f32x4 pf0 = {0, 0, 0, 0}, pf1 = {0, 0, 0, 0};

  auto matvec = [&](f32x4* C) {
#pragma unroll
    for (int np = 0; np < 2; ++np) {
      f32x4 c01 = __builtin_amdgcn_mfma_f32_16x16x32_bf16(
          A[np][1], Bf[1],
          __builtin_amdgcn_mfma_f32_16x16x32_bf16(A[np][0], Bf[0],
                                                  (f32x4){0.f, 0.f, 0.f, 0.f}, 0, 0, 0),
          0, 0, 0);
      f32x4 c23 = __builtin_amdgcn_mfma_f32_16x16x32_bf16(
          A[np][3], Bf[3],
          __builtin_amdgcn_mfma_f32_16x16x32_bf16(A[np][2], Bf[2],
                                                  (f32x4){0.f, 0.f, 0.f, 0.f}, 0, 0, 0),
          0, 0, 0);
      C[np] = c01 + c23;   // two independent 2-chains + one vector add
    }
  };

  auto step = [&](int t, int u) {
    f32x4 C[2];
    matvec(C);
    // scale * 2^(e*L2E) in the MFMA shadow.
    f32x4 se0, se1;
    {
      f32x4 e = er[u][0];
      se0.x = scale * fast_exp2(e.x * L2E); se0.y = scale * fast_exp2(e.y * L2E);
      se0.z = scale * fast_exp2(e.z * L2E); se0.w = scale * fast_exp2(e.w * L2E);
      e = er[u][1];
      se1.x = scale * fast_exp2(e.x * L2E); se1.y = scale * fast_exp2(e.y * L2E);
      se1.z = scale * fast_exp2(e.z * L2E); se1.w = scale * fast_exp2(e.w * L2E);
    }
    Mi += curE0;
    // Ring refill (stays in flight across bar_lds).
    int rn;
    if (fwd) { rn = t + 4; if (rn > HALF - 1) rn = HALF - 1; }
    else     { rn = 1019 - t; if (rn < HALF) rn = HALF; }
    er[u][0] = *(const f32x4*)&eb[(size_t)rn * Kc + jb0];
    er[u][1] = *(const f32x4*)&eb[(size_t)rn * Kc + jb1];

    const int buf = t & 1;
    {
      f32x4 p;
      p.x = C[0].x * se0.x; p.y = C[0].y * se0.y;
      p.z = C[0].z * se0.z; p.w = C[0].w * se0.w;
      pf0 = p;
      uint32_t d0 = (uint32_t)(uint16_t)bf16rne(p.x) | ((uint32_t)(uint16_t)bf16rne(p.y) << 16);
      uint32_t d1 = (uint32_t)(uint16_t)bf16rne(p.z) | ((uint32_t)(uint16_t)bf16rne(p.w) << 16);
      *(uint2*)&pL[buf][b][jb0] = make_uint2(d0, d1);
      p.x = C[1].x * se1.x; p.y = C[1].y * se1.y;
      p.z = C[1].z * se1.z; p.w = C[1].w * se1.w;
      pf1 = p;
      d0 = (uint32_t)(uint16_t)bf16rne(p.x) | ((uint32_t)(uint16_t)bf16rne(p.y) << 16);
      d1 = (uint32_t)(uint16_t)bf16rne(p.z) | ((uint32_t)(uint16_t)bf16rne(p.w) << 16);
      *(uint2*)&pL[buf][b][jb1] = make_uint2(d0, d1);
    }
    if (w == 0 && kq == 0) sSc[buf][b] = C[0].x;
    bar_lds();
#pragma unroll
    for (int tt = 0; tt < 4; ++tt)
      Bf[tt] = *(const bf16x8*)&pL[buf][b][32 * tt + 8 * kq];
    float s0 = sSc[buf][b];
    uint32_t ex = (__float_as_uint(s0) >> 23) & 0xffu;
    curE0 = (int)ex - 127;
    scale = __uint_as_float((254u - ex) << 23);
  };

  // 511 exchanged steps: fwd t=1..511 (alpha_511); bwd ii=1..511 (w_512).
  for (int tb = 1; tb + 3 <= HALF - 1; tb += 4) {
    step(tb, 0); step(tb + 1, 1); step(tb + 2, 2); step(tb + 3, 3);
  }
  step(HALF - 3, 0); step(HALF - 2, 1); step(HALF - 1, 2);

  if (fwd) {
    // alpha_511 = 2^Mi * pf (pf includes ee_511 — correct for fwd).
    *(f32x4*)&ws[(size_t)brow * Kc + jb0] = pf0;
    *(f32x4*)&ws[(size_t)brow * Kc + jb1] = pf1;
    if (tid < ROWS) ws[WS_MIF + rb * ROWS + tid] = (float)Mi;
  } else {
    // Final matvec: v_512 = E w_512. Store C*scale WITHOUT emission
    // (ee_511 belongs to the forward half).
    f32x4 C[2];
    matvec(C);
    Mi += curE0;
    f32x4 p0, p1;
    p0.x = C[0].x * scale; p0.y = C[0].y * scale;
    p0.z = C[0].z * scale; p0.w = C[0].w * scale;
    p1.x = C[1].x * scale; p1.y = C[1].y * scale;
    p1.z = C[1].z * scale; p1.w = C[1].w * scale;
    *(f32x4*)&ws[WS_PB + (size_t)brow * Kc + jb0] = p0;
    *(f32x4*)&ws[WS_PB + (size_t)brow * Kc + jb1] = p1;
    if (tid < ROWS) ws[WS_MIB + rb * ROWS + tid] = (float)Mi;
  }
}

// logZ_b = ln2 * (Mif + Mib + log2(sum_j pf[b][j] * pb[b][j]))
__global__ __launch_bounds__(64, 1) void crf_combine(
    const float* __restrict__ ws, float* __restrict__ out)
{
  const int b = (int)blockIdx.x;
  const int lane = (int)threadIdx.x;
  f2 pf = reinterpret_cast<const f2*>(ws + (size_t)b * Kc)[lane];
  f2 pb = reinterpret_cast<const f2*>(ws + WS_PB + (size_t)b * Kc)[lane];
  float v = pf.x * pb.x + pf.y * pb.y;
#pragma unroll
  for (int off = 32; off; off >>= 1) v += __shfl_down(v, off);
  if (lane == 0)
    out[b] = (ws[WS_MIF + b] + ws[WS_MIB + b] + fast_log2(v)) * LN2;
}

extern "C" void kernel_launch(void* const* d_in, const int* in_sizes, int n_in,
                              void* d_out, int out_size, void* d_ws, size_t ws_size,
                              hipStream_t stream) {
  const float* hs    = (const float*)d_in[0];
  const float* trans = (const float*)d_in[1];
  const float* st    = (const float*)d_in[2];
  const float* en    = (const float*)d_in[3];
  float* ws = (float*)d_ws;   // needs 66048 floats = 264192 B
  crf_fwd_bwd_kernel<<<dim3(2 * Bc / ROWS), dim3(256), 0, stream>>>(hs, trans, st, en, ws);
  crf_combine<<<dim3(Bc), dim3(64), 0, stream>>>(ws, (float*)d_out);
}